// Round 22
// baseline (83.138 us; speedup 1.0000x reference)
//
#include <hip/hip_runtime.h>
#include <hip/hip_bf16.h>

typedef __bf16 bf16x8 __attribute__((ext_vector_type(8)));
typedef __bf16 bf16x4 __attribute__((ext_vector_type(4)));
typedef __bf16 bf16x2 __attribute__((ext_vector_type(2)));
typedef unsigned short u16x4 __attribute__((ext_vector_type(4)));
typedef float f32x4 __attribute__((ext_vector_type(4)));
typedef unsigned long long ull;

__device__ inline unsigned short bfc(float f) {
    __bf16 h = (__bf16)f;
    return __builtin_bit_cast(unsigned short, h);
}
__device__ inline float fbc(unsigned short h) {
    return (float)__builtin_bit_cast(__bf16, h);
}
__device__ inline ull pack4bf(float a, float b, float c, float d) {
    bf16x4 v = {(__bf16)a, (__bf16)b, (__bf16)c, (__bf16)d};
    return __builtin_bit_cast(ull, v);
}
__device__ inline unsigned pack2bf(float a, float b) {
    bf16x2 v = {(__bf16)a, (__bf16)b};
    return __builtin_bit_cast(unsigned, v);
}

__device__ inline void gload_lds16(const void* g, void* l) {
    __builtin_amdgcn_global_load_lds((const __attribute__((address_space(1))) void*)g,
                                     (__attribute__((address_space(3))) void*)l, 16, 0, 0);
}

// meta: [0..16] seg offsets, [17] nch, [304..575] chunk_start, [576..847] chunk_end,
//       [848..863] per-b chunk start, [864..879] per-b chunk end
#define MAXCH 272

// K01: fused prep + GEMM1 (MFMA), native bf16 casts throughout.
__global__ __launch_bounds__(256) void k01_prep_gemm1(const float* __restrict__ x,
                                                      const float* __restrict__ w1,
                                                      const float* __restrict__ b1,
                                                      const float* __restrict__ g1,
                                                      const float* __restrict__ be1,
                                                      const float* __restrict__ m1,
                                                      const float* __restrict__ v1,
                                                      const float* __restrict__ w2,
                                                      const int* __restrict__ length,
                                                      unsigned short* __restrict__ w2p,
                                                      int* __restrict__ meta,
                                                      unsigned short* __restrict__ att1) {
    __shared__ __align__(16) unsigned short st[64 * 256];  // 32 KB out tile
    int tid = threadIdx.x;
    int i = blockIdx.x * 256 + tid;   // w2p slot = (kb, kk, lane)
    if (i < 32768) {
        int kb = i >> 9, kk = (i >> 6) & 7, l = i & 63;
        int col = kb * 16 + (l & 15);
        int kin = kk * 32 + (l >> 4) * 8;
        const float* wp = w2 + (size_t)col * 256 + kin;
        *(ull*)(w2p + (size_t)i * 8)     = pack4bf(wp[0], wp[1], wp[2], wp[3]);
        *(ull*)(w2p + (size_t)i * 8 + 4) = pack4bf(wp[4], wp[5], wp[6], wp[7]);
    }
    if (blockIdx.x == 0 && tid < 64) {
        int lane = tid;
        int b = lane & 15;
        int len = length[b];
        int off = 0, chbase = 0, nch = 0;
        int nchb = (len + 127) >> 7;
#pragma unroll
        for (int j = 0; j < 16; j++) {
            int lj = __shfl(len, j, 64);
            int nj = __shfl(nchb, j, 64);
            if (j < b) { off += lj; chbase += nj; }
            nch += nj;
        }
        int total = __shfl(off + len, 15, 64);
        if (lane < 16) {
            meta[b] = off;
            meta[848 + b] = chbase;
            meta[864 + b] = chbase + nchb;
            if (b == 0) { meta[16] = total; meta[17] = nch; }
            for (int t = 0; t < nchb; t++) {
                int s = off + t * 128;
                int en = off + len < s + 128 ? off + len : s + 128;
                meta[304 + chbase + t] = s;
                meta[576 + chbase + t] = en;
            }
        }
    }
    // ---- GEMM1 via MFMA: block = 64 rows x 256 cols; wave w owns cols w*64..w*64+63 ----
    int row0 = blockIdx.x * 64;
    int lane = tid & 63, wave = tid >> 6;
    int lr = lane & 15, s16 = lane >> 4;

    bf16x8 a[4], b[4];
#pragma unroll
    for (int m = 0; m < 4; m++) {
        const float* xp = x + (size_t)(row0 + m * 16 + lr) * 32 + s16 * 8;
        f32x4 lo = *(const f32x4*)(const void*)xp;
        f32x4 hi = *(const f32x4*)(const void*)(xp + 4);
        a[m] = bf16x8{(__bf16)lo[0], (__bf16)lo[1], (__bf16)lo[2], (__bf16)lo[3],
                      (__bf16)hi[0], (__bf16)hi[1], (__bf16)hi[2], (__bf16)hi[3]};
    }
#pragma unroll
    for (int n = 0; n < 4; n++) {
        const float* wp = w1 + (size_t)(wave * 64 + n * 16 + lr) * 32 + s16 * 8;
        f32x4 lo = *(const f32x4*)(const void*)wp;
        f32x4 hi = *(const f32x4*)(const void*)(wp + 4);
        b[n] = bf16x8{(__bf16)lo[0], (__bf16)lo[1], (__bf16)lo[2], (__bf16)lo[3],
                      (__bf16)hi[0], (__bf16)hi[1], (__bf16)hi[2], (__bf16)hi[3]};
    }
    f32x4 acc[4][4] = {};
#pragma unroll
    for (int m = 0; m < 4; m++)
#pragma unroll
        for (int n = 0; n < 4; n++)
            acc[m][n] = __builtin_amdgcn_mfma_f32_16x16x32_bf16(a[m], b[n], acc[m][n], 0, 0, 0);

    // epilogue: BN1 + ReLU -> st[row_local][j]
    int cc = lane & 15, cr4 = (lane >> 4) * 4;
#pragma unroll
    for (int n = 0; n < 4; n++) {
        int j = wave * 64 + n * 16 + cc;
        float s = g1[j] * rsqrtf(v1[j] + 1e-5f);
        float bias = (b1[j] - m1[j]) * s + be1[j];
#pragma unroll
        for (int m = 0; m < 4; m++) {
#pragma unroll
            for (int rg = 0; rg < 4; rg++) {
                int rl = m * 16 + cr4 + rg;
                float t = fmaf(acc[m][n][rg], s, bias);
                st[rl * 256 + j] = bfc(fmaxf(t, 0.f));
            }
        }
    }
    __syncthreads();
    // coalesced copy-out: 2048 x 16B granules
#pragma unroll
    for (int p = 0; p < 8; p++) {
        int idx = p * 256 + tid;
        *(f32x4*)(void*)(att1 + (size_t)row0 * 256 + idx * 8) =
            *(const f32x4*)(const void*)((const char*)st + idx * 16);
    }
}

// K23: fused GEMM2 + pooling. Round-14 structure; pP bf16; native cvt_pk-friendly casts.
__global__ __launch_bounds__(256, 2) void k23_fused(const unsigned short* __restrict__ att1,
                                                    const unsigned short* __restrict__ w2p,
                                                    const float* __restrict__ x,
                                                    const int* __restrict__ meta,
                                                    const float* __restrict__ b2,
                                                    const float* __restrict__ g2,
                                                    const float* __restrict__ be2,
                                                    const float* __restrict__ m2,
                                                    const float* __restrict__ v2,
                                                    unsigned short* __restrict__ pP,
                                                    float* __restrict__ pS) {
    __shared__ __align__(16) unsigned short As[2][128 * 64];  // 32 KB dbuf; reused as eT[128][128]
    __shared__ __align__(16) unsigned short xT[48 * 128];     // 12 KB (c=32 is the ones-column)
    int flat = blockIdx.x;
    int xcd = flat & 7, q = flat >> 3;
    int ch = (q >> 3) * 8 + xcd;
    int kt = q & 7;
    if (ch >= meta[17]) return;
    int n0 = meta[304 + ch];
    int rows = meta[576 + ch] - n0;
    int col0 = kt * 128;
    int tid = threadIdx.x, lane = tid & 63, wave = tid >> 6;
    int lr = lane & 15, s16 = lane >> 4;
    int wr = wave >> 1, wc = wave & 1;

    auto stage = [&](int t, int buf) {
#pragma unroll
        for (int it = 0; it < 4; it++) {
            int idx = it * 256 + tid;
            int row = idx >> 3, slot = idx & 7;
            int srow = row < rows ? row : rows - 1;
            int g = slot ^ (row & 7);
            gload_lds16(att1 + (size_t)(n0 + srow) * 256 + t * 64 + g * 8,
                        (char*)As + buf * 16384 + it * 4096 + wave * 1024);
        }
    };

    int kb0 = kt * 8 + wc * 4;
    auto loadB = [&](int t, bf16x8 (&bb)[2][4]) {
#pragma unroll
        for (int kk = 0; kk < 2; kk++)
#pragma unroll
            for (int n = 0; n < 4; n++)
                bb[kk][n] = *(const bf16x8*)(const void*)(
                    w2p + (size_t)(((kb0 + n) * 8 + t * 2 + kk) * 64 + lane) * 8);
    };

    bf16x8 b0[2][4], b1[2][4];
    stage(0, 0);
    loadB(0, b0);

#pragma unroll
    for (int p = 0; p < 8; p++) {
        int nb = p * 16 + (tid >> 5) * 2;
        int c = tid & 31;
        float v0 = (nb < rows) ? x[(size_t)(n0 + nb) * 32 + c] : 0.f;
        float v1 = (nb + 1 < rows) ? x[(size_t)(n0 + nb + 1) * 32 + c] : 0.f;
        int byte = c * 256 + ((nb * 2) ^ ((c & 15) << 4));
        *(unsigned*)((char*)xT + byte) = pack2bf(v0, v1);
    }
    if (tid < 128) {
        int byte = 32 * 256 + tid * 2;
        *(unsigned short*)((char*)xT + byte) = (tid < rows) ? bfc(1.f) : (unsigned short)0;
    }
    __syncthreads();

    f32x4 acc[4][4] = {};
#pragma unroll
    for (int t = 0; t < 4; t++) {
        if (t < 3) stage(t + 1, (t & 1) ^ 1);
        if (t == 0) loadB(1, b1);
        else if (t == 1) loadB(2, b0);
        else if (t == 2) loadB(3, b1);
        const char* Ab = (const char*)As + (t & 1) * 16384;
#pragma unroll
        for (int kk = 0; kk < 2; kk++) {
            bf16x8 a[4];
#pragma unroll
            for (int m = 0; m < 4; m++) {
                int row = wr * 64 + m * 16 + lr;
                int slot = (kk * 4 + s16) ^ (row & 7);
                a[m] = *(const bf16x8*)(const void*)(Ab + row * 128 + slot * 16);
            }
#pragma unroll
            for (int m = 0; m < 4; m++)
#pragma unroll
                for (int n = 0; n < 4; n++)
                    acc[m][n] = __builtin_amdgcn_mfma_f32_16x16x32_bf16(
                        a[m], (t & 1) ? b1[kk][n] : b0[kk][n], acc[m][n], 0, 0, 0);
        }
        __syncthreads();
    }

    // ---- epilogue: e = exp(relu(bn2(acc))) -> TRANSPOSED eT[k][n] (b64, &15 swizzle) ----
    char* eT = (char*)As;
#pragma unroll
    for (int nf = 0; nf < 4; nf++) {
        int k = wc * 64 + nf * 16 + lr;
        int kg = col0 + k;
        float sc = g2[kg] * rsqrtf(v2[kg] + 1e-5f);
        float bias = (b2[kg] - m2[kg]) * sc + be2[kg];
#pragma unroll
        for (int m = 0; m < 4; m++) {
            int nbase = wr * 64 + m * 16 + s16 * 4;
            float ev[4];
#pragma unroll
            for (int rg = 0; rg < 4; rg++) {
                float tt = fmaf(acc[m][nf][rg], sc, bias);
                float e = __expf(fmaxf(tt, 0.f));
                ev[rg] = (nbase + rg < rows) ? e : 0.f;
            }
            int byte = k * 256 + ((nbase * 2) ^ ((k & 15) << 4));
            *(ull*)(eT + byte) = pack4bf(ev[0], ev[1], ev[2], ev[3]);
        }
    }
    __syncthreads();

    // ---- pool MFMA: P[k][c] = sum_n eT[k][n] * xT[c][n]; c=32 gives S[k] ----
    f32x4 pacc[2][3] = {};
#pragma unroll
    for (int nc = 0; nc < 128; nc += 32) {
        bf16x8 ea[2], xb[3];
#pragma unroll
        for (int i = 0; i < 2; i++) {
            int k = (wave * 2 + i) * 16 + lr;
            int byte = k * 256 + (((nc + s16 * 8) * 2) ^ ((k & 15) << 4));
            ea[i] = *(const bf16x8*)(const void*)(eT + byte);
        }
#pragma unroll
        for (int j = 0; j < 3; j++) {
            int c = j * 16 + lr;
            int byte = c * 256 + (((nc + s16 * 8) * 2) ^ ((c & 15) << 4));
            xb[j] = *(const bf16x8*)(const void*)((const char*)xT + byte);
        }
#pragma unroll
        for (int i = 0; i < 2; i++)
#pragma unroll
            for (int j = 0; j < 3; j++)
                pacc[i][j] = __builtin_amdgcn_mfma_f32_16x16x32_bf16(ea[i], xb[j], pacc[i][j], 0, 0, 0);
    }

    unsigned short* pPc = pP + (size_t)ch * 32768;
#pragma unroll
    for (int i = 0; i < 2; i++) {
#pragma unroll
        for (int j = 0; j < 3; j++) {
            int c = j * 16 + lr;
#pragma unroll
            for (int rg = 0; rg < 4; rg++) {
                int k = (wave * 2 + i) * 16 + s16 * 4 + rg;
                float v = pacc[i][j][rg];
                if (c < 32) pPc[(col0 + k) * 32 + c] = bfc(v);
                else if (c == 32) pS[ch * 1024 + col0 + k] = v;
            }
        }
    }
}

// K3b: out2[b][k*32+c] = sum_ch P / (sum_ch S * len); 4 bf16 per thread, 512 blocks
__global__ __launch_bounds__(256) void k3b_reduce(const unsigned short* __restrict__ pP,
                                                  const float* __restrict__ pS,
                                                  const int* __restrict__ meta,
                                                  float* __restrict__ out2) {
    int id = blockIdx.x * 256 + threadIdx.x;   // 0..131071
    int base = id * 4;
    int b = base >> 15, rem = base & 32767, k = rem >> 5;
    float P[4] = {};
    float S = 0.f;
    int c0 = meta[848 + b], c1 = meta[864 + b];
    for (int ch = c0; ch < c1; ch++) {
        u16x4 v = *(const u16x4*)(const void*)(pP + (size_t)ch * 32768 + rem);
#pragma unroll
        for (int j = 0; j < 4; j++) P[j] += fbc(v[j]);
        S += pS[ch * 1024 + k];
    }
    float inv = 1.f / (S * (float)(meta[b + 1] - meta[b]));
    f32x4 o = {P[0] * inv, P[1] * inv, P[2] * inv, P[3] * inv};
    *(f32x4*)(void*)(out2 + base) = o;
}

// K4: partial FC — block (jt, dc): 8 j's x all 16 b over a 2048-d slice (2 blocks/CU)
__global__ __launch_bounds__(256) void k4_fc(const float* __restrict__ out2,
                                             const float* __restrict__ fcw,
                                             float* __restrict__ pFC) {
    int jt = blockIdx.x, dc = blockIdx.y;
    int tid = threadIdx.x;
    float acc[16][8] = {};
#pragma unroll
    for (int i = 0; i < 8; i++) {
        int d = dc * 2048 + i * 256 + tid;
        float wv[8];
#pragma unroll
        for (int jj = 0; jj < 8; jj++) wv[jj] = fcw[(size_t)(jt * 8 + jj) * 32768 + d];
#pragma unroll
        for (int bb = 0; bb < 16; bb++) {
            float ov = out2[bb * 32768 + d];
#pragma unroll
            for (int jj = 0; jj < 8; jj++) acc[bb][jj] = fmaf(ov, wv[jj], acc[bb][jj]);
        }
    }
    __shared__ float red[32][257];
#pragma unroll
    for (int p = 0; p < 4; p++) {
#pragma unroll
        for (int q = 0; q < 4; q++)
#pragma unroll
            for (int jj = 0; jj < 8; jj++)
                red[q * 8 + jj][tid] = acc[p * 4 + q][jj];
        __syncthreads();
        int row = tid >> 3, sg = tid & 7;
        float s = 0.f;
        for (int u = sg; u < 256; u += 8) s += red[row][u];
        s += __shfl_down(s, 4, 8);
        s += __shfl_down(s, 2, 8);
        s += __shfl_down(s, 1, 8);
        if (sg == 0) {
            int bb = p * 4 + (row >> 3), jj = row & 7;
            pFC[(dc * 16 + bb) * 256 + jt * 8 + jj] = s;
        }
        __syncthreads();
    }
}

// K45: reduce partials + BN3 + L2-normalize -> out
__global__ __launch_bounds__(256) void k45_fc2(const float* __restrict__ pFC,
                                               const float* __restrict__ fcb,
                                               const float* __restrict__ g3,
                                               const float* __restrict__ be3,
                                               const float* __restrict__ m3,
                                               const float* __restrict__ v3,
                                               float* __restrict__ out) {
    int b = blockIdx.x, j = threadIdx.x;
    float sum = 0.f;
#pragma unroll
    for (int dc = 0; dc < 16; dc++) sum += pFC[(dc * 16 + b) * 256 + j];
    float sc = g3[j] * rsqrtf(v3[j] + 1e-5f);
    float rv = (sum + fcb[j] - m3[j]) * sc + be3[j];
    float sq = rv * rv;
#pragma unroll
    for (int o = 32; o > 0; o >>= 1) sq += __shfl_down(sq, o, 64);
    __shared__ float wsum[4];
    if ((j & 63) == 0) wsum[j >> 6] = sq;
    __syncthreads();
    float tot = wsum[0] + wsum[1] + wsum[2] + wsum[3];
    out[b * 256 + j] = rv / fmaxf(sqrtf(tot), 1e-12f);
}

extern "C" void kernel_launch(void* const* d_in, const int* in_sizes, int n_in,
                              void* d_out, int out_size, void* d_ws, size_t ws_size,
                              hipStream_t stream) {
    const float* x    = (const float*)d_in[0];
    const int*   len  = (const int*)d_in[1];
    const float* w1   = (const float*)d_in[2];
    const float* b1   = (const float*)d_in[3];
    const float* g1   = (const float*)d_in[4];
    const float* be1  = (const float*)d_in[5];
    const float* m1   = (const float*)d_in[6];
    const float* v1   = (const float*)d_in[7];
    const float* w2   = (const float*)d_in[8];
    const float* b2   = (const float*)d_in[9];
    const float* g2   = (const float*)d_in[10];
    const float* be2  = (const float*)d_in[11];
    const float* m2   = (const float*)d_in[12];
    const float* v2   = (const float*)d_in[13];
    const float* fcw  = (const float*)d_in[14];
    const float* fcb  = (const float*)d_in[15];
    const float* g3   = (const float*)d_in[16];
    const float* be3  = (const float*)d_in[17];
    const float* m3   = (const float*)d_in[18];
    const float* v3   = (const float*)d_in[19];

    char* ws = (char*)d_ws;
    int* meta            = (int*)ws;                           // 4 KB
    unsigned short* w2p  = (unsigned short*)(ws + 4096);       // 512 KB -> 528384
    unsigned short* att1 = (unsigned short*)(ws + 528384);     // 16 MB  -> 17305600
    unsigned short* pP   = (unsigned short*)(ws + 17305600);   // 17.83 MB -> 35131392
    float* pS            = (float*)(ws + 35131392);            // 1.1 MB -> 36245504
    float* out2          = (float*)(ws + 36245504);            // 2 MB -> 38342656
    float* pFC           = (float*)(ws + 38342656);            // 256 KB -> 38604800
    float* out           = (float*)d_out;

    hipLaunchKernelGGL(k01_prep_gemm1, dim3(512),   dim3(256), 0, stream,
                       x, w1, b1, g1, be1, m1, v1, w2, len, w2p, meta, att1);
    hipLaunchKernelGGL(k23_fused,  dim3(MAXCH * 8), dim3(256), 0, stream, att1, w2p, x, meta, b2, g2, be2, m2, v2, pP, pS);
    hipLaunchKernelGGL(k3b_reduce, dim3(512),       dim3(256), 0, stream, pP, pS, meta, out2);
    hipLaunchKernelGGL(k4_fc,      dim3(32, 16),    dim3(256), 0, stream, out2, fcw, pFC);
    hipLaunchKernelGGL(k45_fc2,    dim3(16),        dim3(256), 0, stream, pFC, fcb, g3, be3, m3, v3, out);
}

// Round 23
// 78.726 us; speedup vs baseline: 1.0560x; 1.0560x over previous
//
#include <hip/hip_runtime.h>
#include <hip/hip_bf16.h>

typedef __bf16 bf16x8 __attribute__((ext_vector_type(8)));
typedef unsigned short u16x4 __attribute__((ext_vector_type(4)));
typedef unsigned short u16x8 __attribute__((ext_vector_type(8)));
typedef float f32x4 __attribute__((ext_vector_type(4)));
typedef unsigned long long ull;

__device__ inline unsigned short f2bf(float f) {
    unsigned u = __builtin_bit_cast(unsigned, f);
    unsigned r = (u + 0x7fffu + ((u >> 16) & 1u)) >> 16;
    return (unsigned short)r;
}
__device__ inline float bf2f(unsigned short h) {
    unsigned u = ((unsigned)h) << 16;
    return __builtin_bit_cast(float, u);
}

__device__ inline void gload_lds16(const void* g, void* l) {
    __builtin_amdgcn_global_load_lds((const __attribute__((address_space(1))) void*)g,
                                     (__attribute__((address_space(3))) void*)l, 16, 0, 0);
}

// meta: [0..16] seg offsets, [17] nch, [304..575] chunk_start, [576..847] chunk_end,
//       [848..863] per-b chunk start, [864..879] per-b chunk end
#define MAXCH 272

// K01: fused prep + GEMM1 (MFMA).
__global__ __launch_bounds__(256) void k01_prep_gemm1(const float* __restrict__ x,
                                                      const float* __restrict__ w1,
                                                      const float* __restrict__ b1,
                                                      const float* __restrict__ g1,
                                                      const float* __restrict__ be1,
                                                      const float* __restrict__ m1,
                                                      const float* __restrict__ v1,
                                                      const float* __restrict__ w2,
                                                      const int* __restrict__ length,
                                                      unsigned short* __restrict__ w2p,
                                                      int* __restrict__ meta,
                                                      unsigned short* __restrict__ att1) {
    __shared__ __align__(16) unsigned short st[64 * 256];  // 32 KB out tile
    int tid = threadIdx.x;
    int i = blockIdx.x * 256 + tid;   // w2p slot = (kb, kk, lane)
    if (i < 32768) {
        int kb = i >> 9, kk = (i >> 6) & 7, l = i & 63;
        int col = kb * 16 + (l & 15);
        int kin = kk * 32 + (l >> 4) * 8;
        unsigned short v[8];
#pragma unroll
        for (int j = 0; j < 8; j++) v[j] = f2bf(w2[(size_t)col * 256 + kin + j]);
        *(ull*)(w2p + (size_t)i * 8)     = *(ull*)&v[0];
        *(ull*)(w2p + (size_t)i * 8 + 4) = *(ull*)&v[4];
    }
    if (blockIdx.x == 0 && tid < 64) {
        int lane = tid;
        int b = lane & 15;
        int len = length[b];
        int off = 0, chbase = 0, nch = 0;
        int nchb = (len + 127) >> 7;
#pragma unroll
        for (int j = 0; j < 16; j++) {
            int lj = __shfl(len, j, 64);
            int nj = __shfl(nchb, j, 64);
            if (j < b) { off += lj; chbase += nj; }
            nch += nj;
        }
        int total = __shfl(off + len, 15, 64);
        if (lane < 16) {
            meta[b] = off;
            meta[848 + b] = chbase;
            meta[864 + b] = chbase + nchb;
            if (b == 0) { meta[16] = total; meta[17] = nch; }
            for (int t = 0; t < nchb; t++) {
                int s = off + t * 128;
                int en = off + len < s + 128 ? off + len : s + 128;
                meta[304 + chbase + t] = s;
                meta[576 + chbase + t] = en;
            }
        }
    }
    // ---- GEMM1 via MFMA: block = 64 rows x 256 cols; wave w owns cols w*64..w*64+63 ----
    int row0 = blockIdx.x * 64;
    int lane = tid & 63, wave = tid >> 6;
    int lr = lane & 15, s16 = lane >> 4;

    bf16x8 a[4], b[4];
#pragma unroll
    for (int m = 0; m < 4; m++) {
        const float* xp = x + (size_t)(row0 + m * 16 + lr) * 32 + s16 * 8;
        f32x4 lo = *(const f32x4*)(const void*)xp;
        f32x4 hi = *(const f32x4*)(const void*)(xp + 4);
        unsigned short v[8];
#pragma unroll
        for (int j = 0; j < 4; j++) { v[j] = f2bf(lo[j]); v[4 + j] = f2bf(hi[j]); }
        a[m] = *(bf16x8*)v;
    }
#pragma unroll
    for (int n = 0; n < 4; n++) {
        const float* wp = w1 + (size_t)(wave * 64 + n * 16 + lr) * 32 + s16 * 8;
        f32x4 lo = *(const f32x4*)(const void*)wp;
        f32x4 hi = *(const f32x4*)(const void*)(wp + 4);
        unsigned short v[8];
#pragma unroll
        for (int j = 0; j < 4; j++) { v[j] = f2bf(lo[j]); v[4 + j] = f2bf(hi[j]); }
        b[n] = *(bf16x8*)v;
    }
    f32x4 acc[4][4] = {};
#pragma unroll
    for (int m = 0; m < 4; m++)
#pragma unroll
        for (int n = 0; n < 4; n++)
            acc[m][n] = __builtin_amdgcn_mfma_f32_16x16x32_bf16(a[m], b[n], acc[m][n], 0, 0, 0);

    // epilogue: BN1 + ReLU -> st[row_local][j]
    int cc = lane & 15, cr4 = (lane >> 4) * 4;
#pragma unroll
    for (int n = 0; n < 4; n++) {
        int j = wave * 64 + n * 16 + cc;
        float s = g1[j] * rsqrtf(v1[j] + 1e-5f);
        float bias = (b1[j] - m1[j]) * s + be1[j];
#pragma unroll
        for (int m = 0; m < 4; m++) {
#pragma unroll
            for (int rg = 0; rg < 4; rg++) {
                int rl = m * 16 + cr4 + rg;
                float t = fmaf(acc[m][n][rg], s, bias);
                st[rl * 256 + j] = f2bf(fmaxf(t, 0.f));
            }
        }
    }
    __syncthreads();
    // coalesced copy-out: 2048 x 16B granules
#pragma unroll
    for (int p = 0; p < 8; p++) {
        int idx = p * 256 + tid;
        *(f32x4*)(void*)(att1 + (size_t)row0 * 256 + idx * 8) =
            *(const f32x4*)(const void*)((const char*)st + idx * 16);
    }
}

// K23: fused GEMM2 + pooling. Round-14 structure (no keep-alive); pP bf16.
__global__ __launch_bounds__(256, 2) void k23_fused(const unsigned short* __restrict__ att1,
                                                    const unsigned short* __restrict__ w2p,
                                                    const float* __restrict__ x,
                                                    const int* __restrict__ meta,
                                                    const float* __restrict__ b2,
                                                    const float* __restrict__ g2,
                                                    const float* __restrict__ be2,
                                                    const float* __restrict__ m2,
                                                    const float* __restrict__ v2,
                                                    unsigned short* __restrict__ pP,
                                                    float* __restrict__ pS) {
    __shared__ __align__(16) unsigned short As[2][128 * 64];  // 32 KB dbuf; reused as eT[128][128]
    __shared__ __align__(16) unsigned short xT[48 * 128];     // 12 KB (c=32 is the ones-column)
    int flat = blockIdx.x;
    int xcd = flat & 7, q = flat >> 3;
    int ch = (q >> 3) * 8 + xcd;
    int kt = q & 7;
    if (ch >= meta[17]) return;
    int n0 = meta[304 + ch];
    int rows = meta[576 + ch] - n0;
    int col0 = kt * 128;
    int tid = threadIdx.x, lane = tid & 63, wave = tid >> 6;
    int lr = lane & 15, s16 = lane >> 4;
    int wr = wave >> 1, wc = wave & 1;

    auto stage = [&](int t, int buf) {
#pragma unroll
        for (int it = 0; it < 4; it++) {
            int idx = it * 256 + tid;
            int row = idx >> 3, slot = idx & 7;
            int srow = row < rows ? row : rows - 1;
            int g = slot ^ (row & 7);
            gload_lds16(att1 + (size_t)(n0 + srow) * 256 + t * 64 + g * 8,
                        (char*)As + buf * 16384 + it * 4096 + wave * 1024);
        }
    };

    int kb0 = kt * 8 + wc * 4;
    auto loadB = [&](int t, bf16x8 (&bb)[2][4]) {
#pragma unroll
        for (int kk = 0; kk < 2; kk++)
#pragma unroll
            for (int n = 0; n < 4; n++)
                bb[kk][n] = *(const bf16x8*)(const void*)(
                    w2p + (size_t)(((kb0 + n) * 8 + t * 2 + kk) * 64 + lane) * 8);
    };

    bf16x8 b0[2][4], b1[2][4];
    stage(0, 0);
    loadB(0, b0);

#pragma unroll
    for (int p = 0; p < 8; p++) {
        int nb = p * 16 + (tid >> 5) * 2;
        int c = tid & 31;
        float v0 = (nb < rows) ? x[(size_t)(n0 + nb) * 32 + c] : 0.f;
        float v1 = (nb + 1 < rows) ? x[(size_t)(n0 + nb + 1) * 32 + c] : 0.f;
        unsigned pk = ((unsigned)f2bf(v1) << 16) | f2bf(v0);
        int byte = c * 256 + ((nb * 2) ^ ((c & 15) << 4));
        *(unsigned*)((char*)xT + byte) = pk;
    }
    if (tid < 128) {
        int byte = 32 * 256 + tid * 2;
        *(unsigned short*)((char*)xT + byte) = (tid < rows) ? f2bf(1.f) : (unsigned short)0;
    }
    __syncthreads();

    f32x4 acc[4][4] = {};
#pragma unroll
    for (int t = 0; t < 4; t++) {
        if (t < 3) stage(t + 1, (t & 1) ^ 1);
        if (t == 0) loadB(1, b1);
        else if (t == 1) loadB(2, b0);
        else if (t == 2) loadB(3, b1);
        const char* Ab = (const char*)As + (t & 1) * 16384;
#pragma unroll
        for (int kk = 0; kk < 2; kk++) {
            bf16x8 a[4];
#pragma unroll
            for (int m = 0; m < 4; m++) {
                int row = wr * 64 + m * 16 + lr;
                int slot = (kk * 4 + s16) ^ (row & 7);
                a[m] = *(const bf16x8*)(const void*)(Ab + row * 128 + slot * 16);
            }
#pragma unroll
            for (int m = 0; m < 4; m++)
#pragma unroll
                for (int n = 0; n < 4; n++)
                    acc[m][n] = __builtin_amdgcn_mfma_f32_16x16x32_bf16(
                        a[m], (t & 1) ? b1[kk][n] : b0[kk][n], acc[m][n], 0, 0, 0);
        }
        __syncthreads();
    }

    char* eT = (char*)As;
#pragma unroll
    for (int nf = 0; nf < 4; nf++) {
        int k = wc * 64 + nf * 16 + lr;
        int kg = col0 + k;
        float sc = g2[kg] * rsqrtf(v2[kg] + 1e-5f);
        float bias = (b2[kg] - m2[kg]) * sc + be2[kg];
#pragma unroll
        for (int m = 0; m < 4; m++) {
            int nbase = wr * 64 + m * 16 + s16 * 4;
            ull pk = 0;
#pragma unroll
            for (int rg = 0; rg < 4; rg++) {
                float tt = fmaf(acc[m][nf][rg], sc, bias);
                float ev = __expf(fmaxf(tt, 0.f));
                unsigned short h = (nbase + rg < rows) ? f2bf(ev) : (unsigned short)0;
                pk |= ((ull)h) << (16 * rg);
            }
            int byte = k * 256 + ((nbase * 2) ^ ((k & 15) << 4));
            *(ull*)(eT + byte) = pk;
        }
    }
    __syncthreads();

    f32x4 pacc[2][3] = {};
#pragma unroll
    for (int nc = 0; nc < 128; nc += 32) {
        bf16x8 ea[2], xb[3];
#pragma unroll
        for (int i = 0; i < 2; i++) {
            int k = (wave * 2 + i) * 16 + lr;
            int byte = k * 256 + (((nc + s16 * 8) * 2) ^ ((k & 15) << 4));
            ea[i] = *(const bf16x8*)(const void*)(eT + byte);
        }
#pragma unroll
        for (int j = 0; j < 3; j++) {
            int c = j * 16 + lr;
            int byte = c * 256 + (((nc + s16 * 8) * 2) ^ ((c & 15) << 4));
            xb[j] = *(const bf16x8*)(const void*)((const char*)xT + byte);
        }
#pragma unroll
        for (int i = 0; i < 2; i++)
#pragma unroll
            for (int j = 0; j < 3; j++)
                pacc[i][j] = __builtin_amdgcn_mfma_f32_16x16x32_bf16(ea[i], xb[j], pacc[i][j], 0, 0, 0);
    }

    unsigned short* pPc = pP + (size_t)ch * 32768;
#pragma unroll
    for (int i = 0; i < 2; i++) {
#pragma unroll
        for (int j = 0; j < 3; j++) {
            int c = j * 16 + lr;
#pragma unroll
            for (int rg = 0; rg < 4; rg++) {
                int k = (wave * 2 + i) * 16 + s16 * 4 + rg;
                float v = pacc[i][j][rg];
                if (c < 32) pPc[(col0 + k) * 32 + c] = f2bf(v);
                else if (c == 32) pS[ch * 1024 + col0 + k] = v;
            }
        }
    }
}

// K3b: out2[b][k*32+c] = sum_ch P / (sum_ch S * len); 4 bf16 per thread, 512 blocks
__global__ __launch_bounds__(256) void k3b_reduce(const unsigned short* __restrict__ pP,
                                                  const float* __restrict__ pS,
                                                  const int* __restrict__ meta,
                                                  float* __restrict__ out2) {
    int id = blockIdx.x * 256 + threadIdx.x;   // 0..131071
    int base = id * 4;
    int b = base >> 15, rem = base & 32767, k = rem >> 5;
    float P[4] = {};
    float S = 0.f;
    int c0 = meta[848 + b], c1 = meta[864 + b];
    for (int ch = c0; ch < c1; ch++) {
        u16x4 v = *(const u16x4*)(const void*)(pP + (size_t)ch * 32768 + rem);
#pragma unroll
        for (int j = 0; j < 4; j++) P[j] += bf2f(v[j]);
        S += pS[ch * 1024 + k];
    }
    float inv = 1.f / (S * (float)(meta[b + 1] - meta[b]));
    f32x4 o = {P[0] * inv, P[1] * inv, P[2] * inv, P[3] * inv};
    *(f32x4*)(void*)(out2 + base) = o;
}

// K4: partial FC — block (jt, dc): 8 j's x all 16 b over a 2048-d slice (2 blocks/CU)
__global__ __launch_bounds__(256) void k4_fc(const float* __restrict__ out2,
                                             const float* __restrict__ fcw,
                                             float* __restrict__ pFC) {
    int jt = blockIdx.x, dc = blockIdx.y;
    int tid = threadIdx.x;
    float acc[16][8] = {};
#pragma unroll
    for (int i = 0; i < 8; i++) {
        int d = dc * 2048 + i * 256 + tid;
        float wv[8];
#pragma unroll
        for (int jj = 0; jj < 8; jj++) wv[jj] = fcw[(size_t)(jt * 8 + jj) * 32768 + d];
#pragma unroll
        for (int bb = 0; bb < 16; bb++) {
            float ov = out2[bb * 32768 + d];
#pragma unroll
            for (int jj = 0; jj < 8; jj++) acc[bb][jj] = fmaf(ov, wv[jj], acc[bb][jj]);
        }
    }
    __shared__ float red[32][257];
#pragma unroll
    for (int p = 0; p < 4; p++) {
#pragma unroll
        for (int q = 0; q < 4; q++)
#pragma unroll
            for (int jj = 0; jj < 8; jj++)
                red[q * 8 + jj][tid] = acc[p * 4 + q][jj];
        __syncthreads();
        int row = tid >> 3, sg = tid & 7;
        float s = 0.f;
        for (int u = sg; u < 256; u += 8) s += red[row][u];
        s += __shfl_down(s, 4, 8);
        s += __shfl_down(s, 2, 8);
        s += __shfl_down(s, 1, 8);
        if (sg == 0) {
            int bb = p * 4 + (row >> 3), jj = row & 7;
            pFC[(dc * 16 + bb) * 256 + jt * 8 + jj] = s;
        }
        __syncthreads();
    }
}

// K45: reduce partials + BN3 + L2-normalize -> out
__global__ __launch_bounds__(256) void k45_fc2(const float* __restrict__ pFC,
                                               const float* __restrict__ fcb,
                                               const float* __restrict__ g3,
                                               const float* __restrict__ be3,
                                               const float* __restrict__ m3,
                                               const float* __restrict__ v3,
                                               float* __restrict__ out) {
    int b = blockIdx.x, j = threadIdx.x;
    float sum = 0.f;
#pragma unroll
    for (int dc = 0; dc < 16; dc++) sum += pFC[(dc * 16 + b) * 256 + j];
    float sc = g3[j] * rsqrtf(v3[j] + 1e-5f);
    float rv = (sum + fcb[j] - m3[j]) * sc + be3[j];
    float sq = rv * rv;
#pragma unroll
    for (int o = 32; o > 0; o >>= 1) sq += __shfl_down(sq, o, 64);
    __shared__ float wsum[4];
    if ((j & 63) == 0) wsum[j >> 6] = sq;
    __syncthreads();
    float tot = wsum[0] + wsum[1] + wsum[2] + wsum[3];
    out[b * 256 + j] = rv / fmaxf(sqrtf(tot), 1e-12f);
}

extern "C" void kernel_launch(void* const* d_in, const int* in_sizes, int n_in,
                              void* d_out, int out_size, void* d_ws, size_t ws_size,
                              hipStream_t stream) {
    const float* x    = (const float*)d_in[0];
    const int*   len  = (const int*)d_in[1];
    const float* w1   = (const float*)d_in[2];
    const float* b1   = (const float*)d_in[3];
    const float* g1   = (const float*)d_in[4];
    const float* be1  = (const float*)d_in[5];
    const float* m1   = (const float*)d_in[6];
    const float* v1   = (const float*)d_in[7];
    const float* w2   = (const float*)d_in[8];
    const float* b2   = (const float*)d_in[9];
    const float* g2   = (const float*)d_in[10];
    const float* be2  = (const float*)d_in[11];
    const float* m2   = (const float*)d_in[12];
    const float* v2   = (const float*)d_in[13];
    const float* fcw  = (const float*)d_in[14];
    const float* fcb  = (const float*)d_in[15];
    const float* g3   = (const float*)d_in[16];
    const float* be3  = (const float*)d_in[17];
    const float* m3   = (const float*)d_in[18];
    const float* v3   = (const float*)d_in[19];

    char* ws = (char*)d_ws;
    int* meta            = (int*)ws;                           // 4 KB
    unsigned short* w2p  = (unsigned short*)(ws + 4096);       // 512 KB -> 528384
    unsigned short* att1 = (unsigned short*)(ws + 528384);     // 16 MB  -> 17305600
    unsigned short* pP   = (unsigned short*)(ws + 17305600);   // 17.83 MB -> 35131392
    float* pS            = (float*)(ws + 35131392);            // 1.1 MB -> 36245504
    float* out2          = (float*)(ws + 36245504);            // 2 MB -> 38342656
    float* pFC           = (float*)(ws + 38342656);            // 256 KB -> 38604800
    float* out           = (float*)d_out;

    hipLaunchKernelGGL(k01_prep_gemm1, dim3(512),   dim3(256), 0, stream,
                       x, w1, b1, g1, be1, m1, v1, w2, len, w2p, meta, att1);
    hipLaunchKernelGGL(k23_fused,  dim3(MAXCH * 8), dim3(256), 0, stream, att1, w2p, x, meta, b2, g2, be2, m2, v2, pP, pS);
    hipLaunchKernelGGL(k3b_reduce, dim3(512),       dim3(256), 0, stream, pP, pS, meta, out2);
    hipLaunchKernelGGL(k4_fc,      dim3(32, 16),    dim3(256), 0, stream, out2, fcw, pFC);
    hipLaunchKernelGGL(k45_fc2,    dim3(16),        dim3(256), 0, stream, pFC, fcb, g3, be3, m3, v3, out);
}